// Round 11
// baseline (338.040 us; speedup 1.0000x reference)
//
#include <hip/hip_runtime.h>

typedef unsigned short u16;
typedef __bf16 bf16x8 __attribute__((ext_vector_type(8)));
typedef float f32x4 __attribute__((ext_vector_type(4)));

__device__ inline float bf2f(u16 u) {
    unsigned int x = ((unsigned int)u) << 16;
    return __builtin_bit_cast(float, x);
}
__device__ inline u16 f2bf(float f) {
    unsigned int x = __builtin_bit_cast(unsigned int, f);
    return (u16)((x + 0x7FFFu + ((x >> 16) & 1u)) >> 16);
}
__device__ inline float sigm(float v) { return 1.f / (1.f + __expf(-v)); }

__device__ inline uint4 pack8(const float* p) {
    const float4* q = (const float4*)p;
    float4 a = q[0], b = q[1];
    union { u16 h[8]; uint4 v; } u;
    u.h[0] = f2bf(a.x); u.h[1] = f2bf(a.y); u.h[2] = f2bf(a.z); u.h[3] = f2bf(a.w);
    u.h[4] = f2bf(b.x); u.h[5] = f2bf(b.y); u.h[6] = f2bf(b.z); u.h[7] = f2bf(b.w);
    return u.v;
}

// ---------------------------------------------------------------------------
// One fused fp32->bf16 conversion pass: x | in_w | xproj(pad 96->128) | dtw | opw
// chunk ranges (8 elems each): [0,262144) x; [262144,786432) in_w;
// [786432,819200) xpw-pad; [819200,835584) dtw; [835584,1097728) opw.
// ---------------------------------------------------------------------------
__global__ __launch_bounds__(256)
void cvt_all(const float* __restrict__ x, const float* __restrict__ in_w,
             const float* __restrict__ xproj_w, const float* __restrict__ dtw,
             const float* __restrict__ opw,
             u16* __restrict__ x_bf, u16* __restrict__ inw_bf,
             u16* __restrict__ xpw_bf, u16* __restrict__ dtw_bf,
             u16* __restrict__ opw_bf)
{
    int i = blockIdx.x * 256 + threadIdx.x;
    if (i < 262144) {
        ((uint4*)x_bf)[i] = pack8(x + (size_t)i * 8);
    } else if (i < 786432) {
        int j = i - 262144;
        ((uint4*)inw_bf)[j] = pack8(in_w + (size_t)j * 8);
    } else if (i < 819200) {
        int j = i - 786432;
        int row = j >> 8;                       // (j*8)/2048
        ((uint4*)xpw_bf)[j] = (row < 96)
            ? pack8(xproj_w + (size_t)row * 2048 + (j & 255) * 8)
            : make_uint4(0u, 0u, 0u, 0u);
    } else if (i < 835584) {
        int j = i - 819200;
        ((uint4*)dtw_bf)[j] = pack8(dtw + (size_t)j * 8);
    } else {
        int j = i - 835584;
        ((uint4*)opw_bf)[j] = pack8(opw + (size_t)j * 8);
    }
}

// ---------------------------------------------------------------------------
// MFMA NT GEMM, BK=64, register-prefetch double-buffered. bf16 operands
// (B rows must cover full 128-tile; pad upstream). C = A[M,K]*B[N,K]^T over
// k window [z*ksplit,(z+1)*ksplit), output at C + z*zElems elements.
// 128x128 tile, 4 waves x (64x64), 32 MFMA per barrier pair.
// EPI: 0 none; 1 softplus(acc+bias[col]); 2 silu on cols>=2048.
// ---------------------------------------------------------------------------
template<int EPI, bool OUTF32>
__global__ __launch_bounds__(256, 2)
void gemm64(const u16* __restrict__ A, int lda,
            const u16* __restrict__ B, int ldb,
            void* __restrict__ Cout, int ldc,
            int N, int ksplit, size_t zElems,
            const float* __restrict__ bias)
{
    __shared__ u16 sA[128][72];   // 144 B row stride (16B-aligned), ~uniform banks
    __shared__ u16 sB[128][72];

    const int tid  = threadIdx.x;
    const int lane = tid & 63;
    const int wave = tid >> 6;
    const int wm = (wave >> 1) * 64;
    const int wn = (wave & 1) * 64;
    const int m0 = blockIdx.y * 128;
    const int n0 = blockIdx.x * 128;
    const int lm = lane & 15;
    const int kq = (lane >> 4) * 8;
    const int k0 = blockIdx.z * ksplit;

    // chunk c (16B): row c>>3, kcols (c&7)*8 — 4 chunks/thread per matrix
    int row[4], qc[4];
    const u16 *ga[4], *gb[4];
    #pragma unroll
    for (int s = 0; s < 4; ++s) {
        int c = tid + s * 256;
        row[s] = c >> 3;
        qc[s] = (c & 7) * 8;
        ga[s] = A + (size_t)(m0 + row[s]) * lda + k0 + qc[s];
        gb[s] = B + (size_t)(n0 + row[s]) * ldb + k0 + qc[s];
    }

    f32x4 acc[4][4] = {};

    uint4 pa[4], pb[4];
    #pragma unroll
    for (int s = 0; s < 4; ++s) { pa[s] = *(const uint4*)ga[s]; pb[s] = *(const uint4*)gb[s]; }

    for (int kb = 0; kb < ksplit; kb += 64) {
        #pragma unroll
        for (int s = 0; s < 4; ++s) {
            *(uint4*)&sA[row[s]][qc[s]] = pa[s];
            *(uint4*)&sB[row[s]][qc[s]] = pb[s];
        }
        __syncthreads();

        if (kb + 64 < ksplit) {
            #pragma unroll
            for (int s = 0; s < 4; ++s) {
                pa[s] = *(const uint4*)(ga[s] + kb + 64);
                pb[s] = *(const uint4*)(gb[s] + kb + 64);
            }
        }

        #pragma unroll
        for (int ks = 0; ks < 2; ++ks) {
            bf16x8 af[4], bfr[4];
            #pragma unroll
            for (int i = 0; i < 4; ++i)
                af[i] = *(const bf16x8*)&sA[wm + i * 16 + lm][ks * 32 + kq];
            #pragma unroll
            for (int j = 0; j < 4; ++j)
                bfr[j] = *(const bf16x8*)&sB[wn + j * 16 + lm][ks * 32 + kq];
            #pragma unroll
            for (int i = 0; i < 4; ++i)
                #pragma unroll
                for (int j = 0; j < 4; ++j)
                    acc[i][j] = __builtin_amdgcn_mfma_f32_16x16x32_bf16(af[i], bfr[j], acc[i][j], 0, 0, 0);
        }
        __syncthreads();
    }

    // C/D layout: col = lane&15, row = (lane>>4)*4 + reg  [m89/m91-verified]
    #pragma unroll
    for (int i = 0; i < 4; ++i) {
        int crow = m0 + wm + i * 16 + ((lane >> 4) << 2);
        #pragma unroll
        for (int j = 0; j < 4; ++j) {
            int ccol = n0 + wn + j * 16 + lm;
            if (ccol < N) {
                #pragma unroll
                for (int r = 0; r < 4; ++r) {
                    float v = acc[i][j][r];
                    if (EPI == 1) { v += bias[ccol]; v = (v > 20.f) ? v : log1pf(__expf(v)); }
                    if (EPI == 2 && ccol >= 2048) v *= sigm(v);
                    size_t off = (size_t)blockIdx.z * zElems + (size_t)(crow + r) * ldc + ccol;
                    if (OUTF32) ((float*)Cout)[off] = v;
                    else        ((u16*)Cout)[off]   = f2bf(v);
                }
            }
        }
    }
}

// xproj split reduce: 16 fp32 partials -> bf16
__global__ __launch_bounds__(256)
void reduce96(const float* __restrict__ splits, u16* __restrict__ xdbl)
{
    int i = blockIdx.x * 256 + threadIdx.x;   // < 196608
    float acc = 0.f;
    #pragma unroll
    for (int z = 0; z < 16; ++z) acc += splits[(size_t)z * 196608 + i];
    xdbl[i] = f2bf(acc);
}

// out_proj split reduce: 4 bf16 partials -> fp32 d_out (8 elems/thread)
__global__ __launch_bounds__(256)
void reduce_out(const u16* __restrict__ parts, float* __restrict__ out)
{
    int i = blockIdx.x * 256 + threadIdx.x;   // grid 1024
    float acc[8] = {};
    #pragma unroll
    for (int z = 0; z < 4; ++z) {
        uint4 v = ((const uint4*)(parts + (size_t)z * 2097152))[i];
        const u16* h = (const u16*)&v;
        #pragma unroll
        for (int e = 0; e < 8; ++e) acc[e] += bf2f(h[e]);
    }
    float4* o = (float4*)(out + (size_t)i * 8);
    o[0] = make_float4(acc[0], acc[1], acc[2], acc[3]);
    o[1] = make_float4(acc[4], acc[5], acc[6], acc[7]);
}

// ---------------------------------------------------------------------------
// Causal depthwise conv1d (k=4) + bias + SiLU on xr cols [0,2048) -> xs bf16.
// ---------------------------------------------------------------------------
__global__ __launch_bounds__(256)
void conv_silu(const u16* __restrict__ xr, const float* __restrict__ w,
               const float* __restrict__ bias, u16* __restrict__ xs)
{
    int idx = blockIdx.x * 256 + threadIdx.x;
    int d = idx & 2047, t = (idx >> 11) & 1023, b = idx >> 21;
    const u16* base = xr + (size_t)b * 1024 * 4096;
    float acc = bias[d];
    #pragma unroll
    for (int j = 0; j < 4; ++j) {
        int ti = t - 3 + j;
        if (ti >= 0) acc = fmaf(w[d * 4 + j], bf2f(base[(size_t)ti * 4096 + d]), acc);
    }
    xs[idx] = f2bf(acc * sigm(acc));
}

// ---------------------------------------------------------------------------
// Chunked parallel scan (R8-validated). Thread = one d, h[16] in registers.
// ---------------------------------------------------------------------------
template<int PHC>
__global__ __launch_bounds__(256)
void scan_chunk(const u16* __restrict__ deltag, u16* __restrict__ xsg,
                const u16* __restrict__ xdbl, const float* __restrict__ A_log,
                const u16* __restrict__ xr, float* __restrict__ summ,
                float* __restrict__ ssum)
{
    const int tid = threadIdx.x;
    const int d0 = blockIdx.x * 256;
    const int c  = blockIdx.y;
    const int b  = blockIdx.z;
    const int d  = d0 + tid;
    const int tok0 = b * 1024 + c * 32;

    __shared__ u16 s_del[32][256];
    __shared__ u16 s_uu[32][256];
    __shared__ u16 s_bc[32][32];
    __shared__ u16 s_res[PHC ? 32 : 1][PHC ? 256 : 1];
    __shared__ u16 s_y[PHC ? 32 : 1][PHC ? 256 : 1];

    for (int i = tid; i < 1024; i += 256) {
        int tl = i >> 5, v = i & 31;
        size_t tok = (size_t)(tok0 + tl);
        *(uint4*)&s_del[tl][v * 8] = *(const uint4*)&deltag[tok * 4096 + d0 + v * 8];
        *(uint4*)&s_uu[tl][v * 8]  = *(const uint4*)&xsg[tok * 2048 + d0 + v * 8];
        if (PHC)
            *(uint4*)&s_res[tl][v * 8] = *(const uint4*)&xr[tok * 4096 + 2048 + d0 + v * 8];
    }
    for (int i = tid; i < 1024; i += 256) {
        int tl = i >> 5, j = i & 31;
        s_bc[tl][j] = xdbl[(size_t)(tok0 + tl) * 96 + 64 + j];
    }

    float Ar[16], h[16];
    {
        const float4* Ap = (const float4*)(A_log + (size_t)d * 16);
        #pragma unroll
        for (int q = 0; q < 4; ++q) {
            float4 a = Ap[q];
            Ar[q * 4 + 0] = -__expf(a.x); Ar[q * 4 + 1] = -__expf(a.y);
            Ar[q * 4 + 2] = -__expf(a.z); Ar[q * 4 + 3] = -__expf(a.w);
        }
    }
    if (PHC) {
        const float4* hp = (const float4*)&summ[((size_t)(b * 32 + c) * 2048 + d) * 16];
        #pragma unroll
        for (int q = 0; q < 4; ++q) {
            float4 v = hp[q];
            h[q * 4 + 0] = v.x; h[q * 4 + 1] = v.y; h[q * 4 + 2] = v.z; h[q * 4 + 3] = v.w;
        }
    } else {
        #pragma unroll
        for (int n = 0; n < 16; ++n) h[n] = 0.f;
    }
    __syncthreads();

    float S = 0.f;
    #pragma unroll 4
    for (int tl = 0; tl < 32; ++tl) {
        float dlt = bf2f(s_del[tl][tid]);
        float du = dlt * bf2f(s_uu[tl][tid]);
        if (!PHC) S += dlt;
        #pragma unroll
        for (int n = 0; n < 16; ++n)
            h[n] = fmaf(__expf(dlt * Ar[n]), h[n], du * bf2f(s_bc[tl][n]));
        if (PHC) {
            float y = 0.f;
            #pragma unroll
            for (int n = 0; n < 16; ++n)
                y = fmaf(h[n], bf2f(s_bc[tl][16 + n]), y);
            s_y[tl][tid] = f2bf(y * bf2f(s_res[tl][tid]));
        }
    }

    if (!PHC) {
        float4* bp = (float4*)&summ[((size_t)(b * 32 + c) * 2048 + d) * 16];
        #pragma unroll
        for (int q = 0; q < 4; ++q)
            bp[q] = make_float4(h[q * 4], h[q * 4 + 1], h[q * 4 + 2], h[q * 4 + 3]);
        ssum[(size_t)(b * 32 + c) * 2048 + d] = S;
    } else {
        __syncthreads();
        for (int i = tid; i < 1024; i += 256) {
            int tl = i >> 5, v = i & 31;
            *(uint4*)&xsg[(size_t)(tok0 + tl) * 2048 + d0 + v * 8] = *(uint4*)&s_y[tl][v * 8];
        }
    }
}

__global__ __launch_bounds__(256)
void scan_phaseB(float* __restrict__ summ, const float* __restrict__ ssum,
                 const float* __restrict__ A_log)
{
    int g = blockIdx.x * 256 + threadIdx.x;
    int n = g & 15;
    int d = (g >> 4) & 2047;
    int b = g >> 15;
    float An = -__expf(A_log[(size_t)d * 16 + n]);
    float h = 0.f;
    for (int c = 0; c < 32; ++c) {
        size_t idx = ((size_t)(b * 32 + c) * 2048 + d) * 16 + n;
        float bc = summ[idx];
        float Sc = ssum[(size_t)(b * 32 + c) * 2048 + d];
        summ[idx] = h;
        h = fmaf(__expf(An * Sc), h, bc);
    }
}

__global__ void sentinel_kernel(float* out, float v) { out[0] = v; }

// ---------------------------------------------------------------------------
extern "C" void kernel_launch(void* const* d_in, const int* in_sizes, int n_in,
                              void* d_out, int out_size, void* d_ws, size_t ws_size,
                              hipStream_t stream)
{
    const float* x         = (const float*)d_in[0];
    const float* in_w      = (const float*)d_in[1];
    const float* conv_w    = (const float*)d_in[2];
    const float* conv_b    = (const float*)d_in[3];
    const float* xproj_w   = (const float*)d_in[4];
    const float* dtproj_w  = (const float*)d_in[5];
    const float* dtproj_b  = (const float*)d_in[6];
    const float* A_log     = (const float*)d_in[7];
    const float* outproj_w = (const float*)d_in[8];
    float* out = (float*)d_out;

    static const int EXP[9] = {2097152, 4194304, 8192, 2048, 196608, 131072, 2048, 32768, 2097152};
    int bad = -1;
    if (n_in != 9) bad = 9;
    else { for (int i = 0; i < 9; ++i) if (in_sizes[i] != EXP[i]) { bad = i; break; } }
    if (bad < 0 && out_size != 2097152) bad = 10;
    if (bad < 0 && ws_size < 64618496u) bad = 11;   // flat layout high-water (ws ~268MB measured R10)
    if (bad >= 0) {
        sentinel_kernel<<<1, 1, 0, stream>>>(out, 131072.f * (1.f + (float)bad / 16.f));
        return;
    }

    // flat ws layout (64.6 MB high-water; ws ≈ 268 MB per R10 fill counters)
    char* ws = (char*)d_ws;
    u16*   xr     = (u16*)(ws);               // [2048][4096] xs_pre->delta | silu(res); dead after scan -> oparts
    u16*   xs     = (u16*)(ws + 16777216);    // [2048][2048] u -> yg
    u16*   xdbl   = (u16*)(ws + 25165824);    // [2048][96]
    u16*   x_bf   = (u16*)(ws + 25559040);    // 4.19M
    u16*   inw_bf = (u16*)(ws + 29753344);    // 8.39M
    u16*   xpw_bf = (u16*)(ws + 38141952);    // 0.52M (padded 128x2048)
    u16*   dtw_bf = (u16*)(ws + 38666240);    // 0.26M
    u16*   opw_bf = (u16*)(ws + 38928384);    // 4.19M
    float* splits = (float*)(ws + 43122688);  // 16 x [2048][96] f32 = 12.58M
    float* summ   = (float*)(ws + 55705600);  // 8.39M
    float* ssum   = (float*)(ws + 64094208);  // 0.52M -> ends 64618496
    u16*   oparts = xr;                       // 4 x [2048][1024] bf16 (xr dead post-scan)

    // 0) all conversions in one pass
    cvt_all<<<4288, 256, 0, stream>>>(x, in_w, xproj_w, dtproj_w, outproj_w,
                                      x_bf, inw_bf, xpw_bf, dtw_bf, opw_bf);
    // 1) in_proj (+silu on res half): 2048x4096, K=1024, 16 iters
    gemm64<2, false><<<dim3(32, 16, 1), 256, 0, stream>>>(
        x_bf, 1024, inw_bf, 1024, xr, 4096, 4096, 1024, 0, nullptr);
    // 2) conv + silu -> xs
    conv_silu<<<16384, 256, 0, stream>>>(xr, conv_w, conv_b, xs);
    // 3) x_proj split-K=16 (256 blocks, 2 iters) -> fp32 splits -> reduce
    gemm64<0, true><<<dim3(1, 16, 16), 256, 0, stream>>>(
        xs, 2048, xpw_bf, 2048, splits, 96, 96, 128, 196608, nullptr);
    reduce96<<<768, 256, 0, stream>>>(splits, xdbl);
    // 4) delta = softplus(xdbl[:,:64] @ dtw^T + b) -> xr cols [0,2048), 1 iter
    gemm64<1, false><<<dim3(16, 16, 1), 256, 0, stream>>>(
        xdbl, 96, dtw_bf, 64, xr, 4096, 2048, 64, 0, dtproj_b);
    // 5) chunked scan A -> B -> C (yg in-place over xs)
    scan_chunk<0><<<dim3(8, 32, 2), 256, 0, stream>>>(xr, xs, xdbl, A_log, xr, summ, ssum);
    scan_phaseB<<<256, 256, 0, stream>>>(summ, ssum, A_log);
    scan_chunk<1><<<dim3(8, 32, 2), 256, 0, stream>>>(xr, xs, xdbl, A_log, xr, summ, ssum);
    // 6) out_proj split-K=4 (512 blocks, 8 iters) + reduce -> fp32 d_out
    gemm64<0, false><<<dim3(8, 16, 4), 256, 0, stream>>>(
        xs, 2048, opw_bf, 2048, oparts, 1024, 1024, 512, 2097152, nullptr);
    reduce_out<<<1024, 256, 0, stream>>>(oparts, out);
}

// Round 12
// 279.482 us; speedup vs baseline: 1.2095x; 1.2095x over previous
//
#include <hip/hip_runtime.h>

typedef unsigned short u16;
typedef __bf16 bf16x8 __attribute__((ext_vector_type(8)));
typedef float f32x4 __attribute__((ext_vector_type(4)));

__device__ inline float bf2f(u16 u) {
    unsigned int x = ((unsigned int)u) << 16;
    return __builtin_bit_cast(float, x);
}
__device__ inline u16 f2bf(float f) {
    unsigned int x = __builtin_bit_cast(unsigned int, f);
    return (u16)((x + 0x7FFFu + ((x >> 16) & 1u)) >> 16);
}
__device__ inline float sigm(float v) { return 1.f / (1.f + __expf(-v)); }

__device__ inline uint4 pack8(const float* p) {
    const float4* q = (const float4*)p;
    float4 a = q[0], b = q[1];
    union { u16 h[8]; uint4 v; } u;
    u.h[0] = f2bf(a.x); u.h[1] = f2bf(a.y); u.h[2] = f2bf(a.z); u.h[3] = f2bf(a.w);
    u.h[4] = f2bf(b.x); u.h[5] = f2bf(b.y); u.h[6] = f2bf(b.z); u.h[7] = f2bf(b.w);
    return u.v;
}

// ---------------------------------------------------------------------------
// One fused fp32->bf16 conversion pass (R11-validated).
// ---------------------------------------------------------------------------
__global__ __launch_bounds__(256)
void cvt_all(const float* __restrict__ x, const float* __restrict__ in_w,
             const float* __restrict__ xproj_w, const float* __restrict__ dtw,
             const float* __restrict__ opw,
             u16* __restrict__ x_bf, u16* __restrict__ inw_bf,
             u16* __restrict__ xpw_bf, u16* __restrict__ dtw_bf,
             u16* __restrict__ opw_bf)
{
    int i = blockIdx.x * 256 + threadIdx.x;
    if (i < 262144) {
        ((uint4*)x_bf)[i] = pack8(x + (size_t)i * 8);
    } else if (i < 786432) {
        int j = i - 262144;
        ((uint4*)inw_bf)[j] = pack8(in_w + (size_t)j * 8);
    } else if (i < 819200) {
        int j = i - 786432;
        int row = j >> 8;
        ((uint4*)xpw_bf)[j] = (row < 96)
            ? pack8(xproj_w + (size_t)row * 2048 + (j & 255) * 8)
            : make_uint4(0u, 0u, 0u, 0u);
    } else if (i < 835584) {
        int j = i - 819200;
        ((uint4*)dtw_bf)[j] = pack8(dtw + (size_t)j * 8);
    } else {
        int j = i - 835584;
        ((uint4*)opw_bf)[j] = pack8(opw + (size_t)j * 8);
    }
}

// ---------------------------------------------------------------------------
// MFMA NT GEMM (R10-proven engine): BK=32, stride-40 LDS, register prefetch.
// C = A[M,K]*B[N,K]^T over k window [z*ksplit,(z+1)*ksplit), out + z*zElems.
// EPI: 0 none; 1 softplus(acc+bias); 2 silu cols>=2048.
// STAGED: bf16 epilogue through LDS -> full-line coalesced writes
//         (A/B experiment vs scattered path; fp32 path always scattered —
//          quad covers a full 64B sector so no amplification).
// ---------------------------------------------------------------------------
template<int EPI, bool OUTF32, bool STAGED>
__global__ __launch_bounds__(256, 2)
void gemm2(const u16* __restrict__ A, int lda,
           const u16* __restrict__ B, int ldb,
           void* __restrict__ Cout, int ldc,
           int N, int ksplit, size_t zElems,
           const float* __restrict__ bias)
{
    __shared__ u16 smem[10240];                 // 20480 B: sA | sB; epilogue reuses as sC
    u16 (*sA)[40] = (u16(*)[40])smem;
    u16 (*sB)[40] = (u16(*)[40])(smem + 5120);

    const int tid  = threadIdx.x;
    const int lane = tid & 63;
    const int wave = tid >> 6;
    const int wm = (wave >> 1) * 64;
    const int wn = (wave & 1) * 64;
    const int m0 = blockIdx.y * 128;
    const int n0 = blockIdx.x * 128;
    const int lm = lane & 15;
    const int kq = (lane >> 4) * 8;
    const int k0 = blockIdx.z * ksplit;

    const int r0 = tid >> 2, q0 = (tid & 3) * 8;
    const int r1 = (tid + 256) >> 2, q1 = ((tid + 256) & 3) * 8;
    const u16* gA0 = A + (size_t)(m0 + r0) * lda + k0 + q0;
    const u16* gA1 = A + (size_t)(m0 + r1) * lda + k0 + q1;
    const u16* gB0 = B + (size_t)(n0 + r0) * ldb + k0 + q0;
    const u16* gB1 = B + (size_t)(n0 + r1) * ldb + k0 + q1;

    f32x4 acc[4][4] = {};

    uint4 pa0 = *(const uint4*)gA0, pa1 = *(const uint4*)gA1;
    uint4 pb0 = *(const uint4*)gB0, pb1 = *(const uint4*)gB1;

    for (int kb = 0; kb < ksplit; kb += 32) {
        *(uint4*)&sA[r0][q0] = pa0;
        *(uint4*)&sA[r1][q1] = pa1;
        *(uint4*)&sB[r0][q0] = pb0;
        *(uint4*)&sB[r1][q1] = pb1;
        __syncthreads();

        if (kb + 32 < ksplit) {
            pa0 = *(const uint4*)(gA0 + kb + 32);
            pa1 = *(const uint4*)(gA1 + kb + 32);
            pb0 = *(const uint4*)(gB0 + kb + 32);
            pb1 = *(const uint4*)(gB1 + kb + 32);
        }

        bf16x8 af[4], bfr[4];
        #pragma unroll
        for (int i = 0; i < 4; ++i)
            af[i] = *(const bf16x8*)&sA[wm + i * 16 + lm][kq];
        #pragma unroll
        for (int j = 0; j < 4; ++j)
            bfr[j] = *(const bf16x8*)&sB[wn + j * 16 + lm][kq];
        #pragma unroll
        for (int i = 0; i < 4; ++i)
            #pragma unroll
            for (int j = 0; j < 4; ++j)
                acc[i][j] = __builtin_amdgcn_mfma_f32_16x16x32_bf16(af[i], bfr[j], acc[i][j], 0, 0, 0);
        __syncthreads();
    }

    // C/D layout: col = lane&15, row = (lane>>4)*4 + reg  [m89/m91-verified]
    if (STAGED && !OUTF32) {
        // coalesced bf16 epilogue: half-tile (64x128) staged in LDS, full-line writes
        u16 (*sC)[132] = (u16(*)[132])smem;     // 64*132*2 = 16896 B <= 20480
        #pragma unroll
        for (int half = 0; half < 2; ++half) {
            if ((wave >> 1) == half) {
                #pragma unroll
                for (int i = 0; i < 4; ++i) {
                    int lr = i * 16 + ((lane >> 4) << 2);
                    #pragma unroll
                    for (int j = 0; j < 4; ++j) {
                        int ccol = n0 + wn + j * 16 + lm;
                        #pragma unroll
                        for (int r = 0; r < 4; ++r) {
                            float v = acc[i][j][r];
                            if (EPI == 1) { v += bias[ccol]; v = (v > 20.f) ? v : log1pf(__expf(v)); }
                            if (EPI == 2 && ccol >= 2048) v *= sigm(v);
                            sC[lr + r][wn + j * 16 + lm] = f2bf(v);
                        }
                    }
                }
            }
            __syncthreads();
            #pragma unroll
            for (int s = 0; s < 4; ++s) {
                int c = tid + s * 256;
                int rr = c >> 4, cc = (c & 15) * 8;
                if (n0 + cc < N)
                    *(uint4*)((u16*)Cout + (size_t)blockIdx.z * zElems
                              + (size_t)(m0 + half * 64 + rr) * ldc + n0 + cc) = *(uint4*)&sC[rr][cc];
            }
            __syncthreads();
        }
    } else {
        #pragma unroll
        for (int i = 0; i < 4; ++i) {
            int crow = m0 + wm + i * 16 + ((lane >> 4) << 2);
            #pragma unroll
            for (int j = 0; j < 4; ++j) {
                int ccol = n0 + wn + j * 16 + lm;
                if (ccol < N) {
                    #pragma unroll
                    for (int r = 0; r < 4; ++r) {
                        float v = acc[i][j][r];
                        if (EPI == 1) { v += bias[ccol]; v = (v > 20.f) ? v : log1pf(__expf(v)); }
                        if (EPI == 2 && ccol >= 2048) v *= sigm(v);
                        size_t off = (size_t)blockIdx.z * zElems + (size_t)(crow + r) * ldc + ccol;
                        if (OUTF32) ((float*)Cout)[off] = v;
                        else        ((u16*)Cout)[off]   = f2bf(v);
                    }
                }
            }
        }
    }
}

// xproj split reduce: 16 fp32 partials -> bf16
__global__ __launch_bounds__(256)
void reduce96(const float* __restrict__ splits, u16* __restrict__ xdbl)
{
    int i = blockIdx.x * 256 + threadIdx.x;
    float acc = 0.f;
    #pragma unroll
    for (int z = 0; z < 16; ++z) acc += splits[(size_t)z * 196608 + i];
    xdbl[i] = f2bf(acc);
}

// out_proj split reduce: 4 bf16 partials -> fp32 d_out
__global__ __launch_bounds__(256)
void reduce_out(const u16* __restrict__ parts, float* __restrict__ out)
{
    int i = blockIdx.x * 256 + threadIdx.x;
    float acc[8] = {};
    #pragma unroll
    for (int z = 0; z < 4; ++z) {
        uint4 v = ((const uint4*)(parts + (size_t)z * 2097152))[i];
        const u16* h = (const u16*)&v;
        #pragma unroll
        for (int e = 0; e < 8; ++e) acc[e] += bf2f(h[e]);
    }
    float4* o = (float4*)(out + (size_t)i * 8);
    o[0] = make_float4(acc[0], acc[1], acc[2], acc[3]);
    o[1] = make_float4(acc[4], acc[5], acc[6], acc[7]);
}

// ---------------------------------------------------------------------------
// Causal depthwise conv1d (k=4) + bias + SiLU on xr cols [0,2048) -> xs bf16.
// ---------------------------------------------------------------------------
__global__ __launch_bounds__(256)
void conv_silu(const u16* __restrict__ xr, const float* __restrict__ w,
               const float* __restrict__ bias, u16* __restrict__ xs)
{
    int idx = blockIdx.x * 256 + threadIdx.x;
    int d = idx & 2047, t = (idx >> 11) & 1023, b = idx >> 21;
    const u16* base = xr + (size_t)b * 1024 * 4096;
    float acc = bias[d];
    #pragma unroll
    for (int j = 0; j < 4; ++j) {
        int ti = t - 3 + j;
        if (ti >= 0) acc = fmaf(w[d * 4 + j], bf2f(base[(size_t)ti * 4096 + d]), acc);
    }
    xs[idx] = f2bf(acc * sigm(acc));
}

// ---------------------------------------------------------------------------
// Chunked parallel scan (R8-validated). Thread = one d, h[16] in registers.
// ---------------------------------------------------------------------------
template<int PHC>
__global__ __launch_bounds__(256)
void scan_chunk(const u16* __restrict__ deltag, u16* __restrict__ xsg,
                const u16* __restrict__ xdbl, const float* __restrict__ A_log,
                const u16* __restrict__ xr, float* __restrict__ summ,
                float* __restrict__ ssum)
{
    const int tid = threadIdx.x;
    const int d0 = blockIdx.x * 256;
    const int c  = blockIdx.y;
    const int b  = blockIdx.z;
    const int d  = d0 + tid;
    const int tok0 = b * 1024 + c * 32;

    __shared__ u16 s_del[32][256];
    __shared__ u16 s_uu[32][256];
    __shared__ u16 s_bc[32][32];
    __shared__ u16 s_res[PHC ? 32 : 1][PHC ? 256 : 1];
    __shared__ u16 s_y[PHC ? 32 : 1][PHC ? 256 : 1];

    for (int i = tid; i < 1024; i += 256) {
        int tl = i >> 5, v = i & 31;
        size_t tok = (size_t)(tok0 + tl);
        *(uint4*)&s_del[tl][v * 8] = *(const uint4*)&deltag[tok * 4096 + d0 + v * 8];
        *(uint4*)&s_uu[tl][v * 8]  = *(const uint4*)&xsg[tok * 2048 + d0 + v * 8];
        if (PHC)
            *(uint4*)&s_res[tl][v * 8] = *(const uint4*)&xr[tok * 4096 + 2048 + d0 + v * 8];
    }
    for (int i = tid; i < 1024; i += 256) {
        int tl = i >> 5, j = i & 31;
        s_bc[tl][j] = xdbl[(size_t)(tok0 + tl) * 96 + 64 + j];
    }

    float Ar[16], h[16];
    {
        const float4* Ap = (const float4*)(A_log + (size_t)d * 16);
        #pragma unroll
        for (int q = 0; q < 4; ++q) {
            float4 a = Ap[q];
            Ar[q * 4 + 0] = -__expf(a.x); Ar[q * 4 + 1] = -__expf(a.y);
            Ar[q * 4 + 2] = -__expf(a.z); Ar[q * 4 + 3] = -__expf(a.w);
        }
    }
    if (PHC) {
        const float4* hp = (const float4*)&summ[((size_t)(b * 32 + c) * 2048 + d) * 16];
        #pragma unroll
        for (int q = 0; q < 4; ++q) {
            float4 v = hp[q];
            h[q * 4 + 0] = v.x; h[q * 4 + 1] = v.y; h[q * 4 + 2] = v.z; h[q * 4 + 3] = v.w;
        }
    } else {
        #pragma unroll
        for (int n = 0; n < 16; ++n) h[n] = 0.f;
    }
    __syncthreads();

    float S = 0.f;
    #pragma unroll 4
    for (int tl = 0; tl < 32; ++tl) {
        float dlt = bf2f(s_del[tl][tid]);
        float du = dlt * bf2f(s_uu[tl][tid]);
        if (!PHC) S += dlt;
        #pragma unroll
        for (int n = 0; n < 16; ++n)
            h[n] = fmaf(__expf(dlt * Ar[n]), h[n], du * bf2f(s_bc[tl][n]));
        if (PHC) {
            float y = 0.f;
            #pragma unroll
            for (int n = 0; n < 16; ++n)
                y = fmaf(h[n], bf2f(s_bc[tl][16 + n]), y);
            s_y[tl][tid] = f2bf(y * bf2f(s_res[tl][tid]));
        }
    }

    if (!PHC) {
        float4* bp = (float4*)&summ[((size_t)(b * 32 + c) * 2048 + d) * 16];
        #pragma unroll
        for (int q = 0; q < 4; ++q)
            bp[q] = make_float4(h[q * 4], h[q * 4 + 1], h[q * 4 + 2], h[q * 4 + 3]);
        ssum[(size_t)(b * 32 + c) * 2048 + d] = S;
    } else {
        __syncthreads();
        for (int i = tid; i < 1024; i += 256) {
            int tl = i >> 5, v = i & 31;
            *(uint4*)&xsg[(size_t)(tok0 + tl) * 2048 + d0 + v * 8] = *(uint4*)&s_y[tl][v * 8];
        }
    }
}

__global__ __launch_bounds__(256)
void scan_phaseB(float* __restrict__ summ, const float* __restrict__ ssum,
                 const float* __restrict__ A_log)
{
    int g = blockIdx.x * 256 + threadIdx.x;
    int n = g & 15;
    int d = (g >> 4) & 2047;
    int b = g >> 15;
    float An = -__expf(A_log[(size_t)d * 16 + n]);
    float h = 0.f;
    for (int c = 0; c < 32; ++c) {
        size_t idx = ((size_t)(b * 32 + c) * 2048 + d) * 16 + n;
        float bc = summ[idx];
        float Sc = ssum[(size_t)(b * 32 + c) * 2048 + d];
        summ[idx] = h;
        h = fmaf(__expf(An * Sc), h, bc);
    }
}

__global__ void sentinel_kernel(float* out, float v) { out[0] = v; }

// ---------------------------------------------------------------------------
extern "C" void kernel_launch(void* const* d_in, const int* in_sizes, int n_in,
                              void* d_out, int out_size, void* d_ws, size_t ws_size,
                              hipStream_t stream)
{
    const float* x         = (const float*)d_in[0];
    const float* in_w      = (const float*)d_in[1];
    const float* conv_w    = (const float*)d_in[2];
    const float* conv_b    = (const float*)d_in[3];
    const float* xproj_w   = (const float*)d_in[4];
    const float* dtproj_w  = (const float*)d_in[5];
    const float* dtproj_b  = (const float*)d_in[6];
    const float* A_log     = (const float*)d_in[7];
    const float* outproj_w = (const float*)d_in[8];
    float* out = (float*)d_out;

    static const int EXP[9] = {2097152, 4194304, 8192, 2048, 196608, 131072, 2048, 32768, 2097152};
    int bad = -1;
    if (n_in != 9) bad = 9;
    else { for (int i = 0; i < 9; ++i) if (in_sizes[i] != EXP[i]) { bad = i; break; } }
    if (bad < 0 && out_size != 2097152) bad = 10;
    if (bad < 0 && ws_size < 64618496u) bad = 11;
    if (bad >= 0) {
        sentinel_kernel<<<1, 1, 0, stream>>>(out, 131072.f * (1.f + (float)bad / 16.f));
        return;
    }

    // flat ws layout (64.6 MB high-water; ws ~268 MB measured R10)
    char* ws = (char*)d_ws;
    u16*   xr     = (u16*)(ws);               // [2048][4096]
    u16*   xs     = (u16*)(ws + 16777216);    // [2048][2048]
    u16*   xdbl   = (u16*)(ws + 25165824);    // [2048][96]
    u16*   x_bf   = (u16*)(ws + 25559040);
    u16*   inw_bf = (u16*)(ws + 29753344);
    u16*   xpw_bf = (u16*)(ws + 38141952);
    u16*   dtw_bf = (u16*)(ws + 38666240);
    u16*   opw_bf = (u16*)(ws + 38928384);
    float* splits = (float*)(ws + 43122688);  // 16 x [2048][96] f32
    float* summ   = (float*)(ws + 55705600);
    float* ssum   = (float*)(ws + 64094208);
    u16*   oparts = xr;                       // xr dead post-scan

    // 0) fused conversions
    cvt_all<<<4288, 256, 0, stream>>>(x, in_w, xproj_w, dtproj_w, outproj_w,
                                      x_bf, inw_bf, xpw_bf, dtw_bf, opw_bf);
    // 1) in_proj (+silu), STAGED coalesced epilogue
    gemm2<2, false, true><<<dim3(32, 16, 1), 256, 0, stream>>>(
        x_bf, 1024, inw_bf, 1024, xr, 4096, 4096, 1024, 0, nullptr);
    // 2) conv + silu -> xs
    conv_silu<<<16384, 256, 0, stream>>>(xr, conv_w, conv_b, xs);
    // 3) x_proj split-K=16 (fp32 scattered epilogue = full sectors, no amp)
    gemm2<0, true, false><<<dim3(1, 16, 16), 256, 0, stream>>>(
        xs, 2048, xpw_bf, 2048, splits, 96, 96, 128, 196608, nullptr);
    reduce96<<<768, 256, 0, stream>>>(splits, xdbl);
    // 4) dt_proj + softplus -> xr cols [0,2048), STAGED
    gemm2<1, false, true><<<dim3(16, 16, 1), 256, 0, stream>>>(
        xdbl, 96, dtw_bf, 64, xr, 4096, 2048, 64, 0, dtproj_b);
    // 5) chunked scan A -> B -> C
    scan_chunk<0><<<dim3(8, 32, 2), 256, 0, stream>>>(xr, xs, xdbl, A_log, xr, summ, ssum);
    scan_phaseB<<<256, 256, 0, stream>>>(summ, ssum, A_log);
    scan_chunk<1><<<dim3(8, 32, 2), 256, 0, stream>>>(xr, xs, xdbl, A_log, xr, summ, ssum);
    // 6) out_proj split-K=4, SCATTERED bf16 epilogue (A/B control) + reduce
    gemm2<0, false, false><<<dim3(8, 16, 4), 256, 0, stream>>>(
        xs, 2048, opw_bf, 2048, oparts, 1024, 1024, 512, 2097152, nullptr);
    reduce_out<<<1024, 256, 0, stream>>>(oparts, out);
}